// Round 5
// baseline (179.101 us; speedup 1.0000x reference)
//
#include <hip/hip_runtime.h>
#include <hip/hip_bf16.h>
#include <stdint.h>

#define DEV_INLINE __device__ __forceinline__

typedef short          short8 __attribute__((ext_vector_type(8)));   // MFMA A/B operand (8 bf16)
typedef unsigned short u16;
typedef unsigned short u16x8  __attribute__((ext_vector_type(8)));
typedef float          f32x4  __attribute__((ext_vector_type(4)));

constexpr float EPSV = 1e-5f;

// ---- d_ws layout (bytes) ----
//     0 : Wsh  frags bf16[16][64][8]  fid = kk*8+nt            (16384 B)
// 16384 : Wexp frags bf16[48][64][8]  fid = (s*4+kk)*4+nt      (49152 B)
// 65536 : sc[128] f32   (bn_gamma * rsqrt(var+eps))            (512 B)
// 66048 : sh[128] f32   ((b_sh-mean)*sc + bn_beta)             (512 B)
// 66560 : W_gfp[20][16] f32, row 19 = 0                        (1280 B)
// total 67840 B

static DEV_INLINE u16 f2bf(float f) {
    return __builtin_bit_cast(u16, __float2bfloat16(f));   // RNE
}

// B-fragment convention (HW-verified in round 4): for frag (kk,nt), lane l,
// element j:  value = W[k = kk*32 + (l>>4)*8 + j][col = nt*16 + (l&15)].
__global__ void prep_kernel(const float* __restrict__ W_gf,
                            const float* __restrict__ W_sh, const float* __restrict__ b_sh,
                            const float* __restrict__ bn_g, const float* __restrict__ bn_b,
                            const float* __restrict__ bn_m, const float* __restrict__ bn_v,
                            const float* __restrict__ Wexp,
                            unsigned char* __restrict__ ws)
{
    const int gid = blockIdx.x * blockDim.x + threadIdx.x;   // 32768 threads
    u16*   wshF = (u16*)ws;
    u16*   wexF = (u16*)(ws + 16384);
    float* scp  = (float*)(ws + 65536);
    float* shp  = (float*)(ws + 66048);
    float* wgp  = (float*)(ws + 66560);

    if (gid < 8192) {                       // Wsh frags (K padded 48->64 with zeros)
        const int fid = gid >> 9, l = (gid >> 3) & 63, j = gid & 7;
        const int kk = fid >> 3, nt = fid & 7;
        const int k = kk*32 + ((l >> 4) << 3) + j;
        const int c = nt*16 + (l & 15);
        wshF[gid] = f2bf((k < 48) ? W_sh[k*128 + c] : 0.f);
    } else {                                // Wexp frags, all K=128 real
        const int id = gid - 8192;
        const int fid = id >> 9, l = (id >> 3) & 63, j = id & 7;
        const int s = fid >> 4, kk = (fid >> 2) & 3, nt = fid & 3;
        const int k = kk*32 + ((l >> 4) << 3) + j;
        const int d = nt*16 + (l & 15);
        wexF[id] = f2bf(Wexp[s*8192 + k*64 + d]);
    }
    if (gid < 128) {
        const float sc = bn_g[gid] * rsqrtf(bn_v[gid] + EPSV);
        scp[gid] = sc;
        shp[gid] = (b_sh[gid] - bn_m[gid]) * sc + bn_b[gid];
    }
    if (gid < 320) {                        // padded W_gf (20 rows, row 19 zero)
        const int f = gid >> 4, e = gid & 15;
        wgp[gid] = (f < 19) ? W_gf[f*16 + e] : 0.f;
    }
}

// swizzled per-wave S slice [32 r][128 j], 16B-group XOR -> conflict-free b128 reads
#define SIDX(r,j)  (((r)<<7) + ((((j)>>3) ^ ((r)&15))<<3) + ((j)&7))

__global__ __launch_bounds__(256) void fused_kernel(
    const int*   __restrict__ home,  const int* __restrict__ away,
    const float* __restrict__ gfeat, const int* __restrict__ sport,
    const float* __restrict__ emb_h, const float* __restrict__ emb_a,
    const float* __restrict__ b_gf,
    const float* __restrict__ bexp,
    const float* __restrict__ ln_g,  const float* __restrict__ ln_b,
    const float* __restrict__ wout,  const float* __restrict__ bo,
    const unsigned char* __restrict__ ws,
    float* __restrict__ out)
{
    __shared__ __align__(16) u16 Sl[4][32 * 128];   // 32 KiB total, 8 KiB per wave (PRIVATE)

    const int tid  = threadIdx.x;
    const int lane = tid & 63;
    const int w    = tid >> 6;
    const int llo  = lane & 15;
    const int lhi  = lane >> 4;
    const int r0w  = blockIdx.x * 128 + w * 32;     // this wave's 32 rows

    const u16*   wshF = (const u16*)ws;
    const u16*   wexF = (const u16*)(ws + 16384);
    const float* scp  = (const float*)(ws + 65536);
    const float* shp  = (const float*)(ws + 66048);
    const float* wgp  = (const float*)(ws + 66560);

    // ============ build A-fragments directly in registers (no LDS, no barrier) ============
    short8 a[2][2];
    {   // kk=0: k 0..31 = [home emb | away emb]; lane's 8-elem slice = one 32B half-row
        const int*   idxp = (lhi < 2) ? home  : away;
        const float* tab  = (lhi < 2) ? emb_h : emb_a;
        const int    off  = (lhi & 1) * 8;
#pragma unroll
        for (int mt = 0; mt < 2; ++mt) {
            const int r = r0w + mt*16 + llo;
            const float* rp = tab + (size_t)idxp[r] * 16 + off;
            const float4 v0 = *(const float4*)rp;
            const float4 v1 = *(const float4*)(rp + 4);
            u16x8 p;
            p[0]=f2bf(v0.x); p[1]=f2bf(v0.y); p[2]=f2bf(v0.z); p[3]=f2bf(v0.w);
            p[4]=f2bf(v1.x); p[5]=f2bf(v1.y); p[6]=f2bf(v1.z); p[7]=f2bf(v1.w);
            a[mt][0] = __builtin_bit_cast(short8, p);
        }
    }
    {   // kk=1: k 32..47 = relu(gf @ W_gf + b); k 48..63 = zero pad.
        // f-loop split across lane^32 partners: lhi&1 picks e-slice, lhi>>1 picks f-half.
        const int eo = (lhi & 1) * 8;
        const int f0 = (lhi >> 1) * 10;
        float p0[8] = {0,0,0,0,0,0,0,0}, p1[8] = {0,0,0,0,0,0,0,0};
#pragma unroll
        for (int i = 0; i < 10; ++i) {
            const int f  = f0 + i;
            const int fc = (f < 19) ? f : 18;          // safe gfeat addr; wgp row 19 is zero
            const float4 w0 = *(const float4*)(wgp + f*16 + eo);
            const float4 w1 = *(const float4*)(wgp + f*16 + eo + 4);
            const float g0 = gfeat[(size_t)(r0w + llo)      * 19 + fc];
            const float g1 = gfeat[(size_t)(r0w + 16 + llo) * 19 + fc];
            p0[0]=fmaf(g0,w0.x,p0[0]); p0[1]=fmaf(g0,w0.y,p0[1]); p0[2]=fmaf(g0,w0.z,p0[2]); p0[3]=fmaf(g0,w0.w,p0[3]);
            p0[4]=fmaf(g0,w1.x,p0[4]); p0[5]=fmaf(g0,w1.y,p0[5]); p0[6]=fmaf(g0,w1.z,p0[6]); p0[7]=fmaf(g0,w1.w,p0[7]);
            p1[0]=fmaf(g1,w0.x,p1[0]); p1[1]=fmaf(g1,w0.y,p1[1]); p1[2]=fmaf(g1,w0.z,p1[2]); p1[3]=fmaf(g1,w0.w,p1[3]);
            p1[4]=fmaf(g1,w1.x,p1[4]); p1[5]=fmaf(g1,w1.y,p1[5]); p1[6]=fmaf(g1,w1.z,p1[6]); p1[7]=fmaf(g1,w1.w,p1[7]);
        }
        const float4 bg0 = *(const float4*)(b_gf + eo);
        const float4 bg1 = *(const float4*)(b_gf + eo + 4);
        const float bg[8] = {bg0.x,bg0.y,bg0.z,bg0.w,bg1.x,bg1.y,bg1.z,bg1.w};
        u16x8 q0, q1;
#pragma unroll
        for (int j = 0; j < 8; ++j) {
            const float s0 = p0[j] + __shfl_xor(p0[j], 32);
            const float s1 = p1[j] + __shfl_xor(p1[j], 32);
            q0[j] = (lhi < 2) ? f2bf(fmaxf(s0 + bg[j], 0.f)) : (u16)0;
            q1[j] = (lhi < 2) ? f2bf(fmaxf(s1 + bg[j], 0.f)) : (u16)0;
        }
        a[0][1] = __builtin_bit_cast(short8, q0);
        a[1][1] = __builtin_bit_cast(short8, q1);
    }

    // ============ S = X @ Wsh, BN+ReLU fold, to wave-private LDS slice ============
    u16* sl = &Sl[w][0];
#pragma unroll
    for (int nt = 0; nt < 8; ++nt) {
        const short8 b0 = *(const short8*)(wshF + (0*8 + nt)*512 + lane*8);
        const short8 b1 = *(const short8*)(wshF + (1*8 + nt)*512 + lane*8);
        f32x4 c0 = {0.f,0.f,0.f,0.f}, c1 = {0.f,0.f,0.f,0.f};
        c0 = __builtin_amdgcn_mfma_f32_16x16x32_bf16(a[0][0], b0, c0, 0, 0, 0);
        c0 = __builtin_amdgcn_mfma_f32_16x16x32_bf16(a[0][1], b1, c0, 0, 0, 0);
        c1 = __builtin_amdgcn_mfma_f32_16x16x32_bf16(a[1][0], b0, c1, 0, 0, 0);
        c1 = __builtin_amdgcn_mfma_f32_16x16x32_bf16(a[1][1], b1, c1, 0, 0, 0);
        const int col = nt*16 + llo;
        const float sc = scp[col], sh = shp[col];
#pragma unroll
        for (int e = 0; e < 4; ++e) {
            sl[SIDX(lhi*4 + e,      col)] = f2bf(fmaxf(fmaf(c0[e], sc, sh), 0.f));
            sl[SIDX(16 + lhi*4 + e, col)] = f2bf(fmaxf(fmaf(c1[e], sc, sh), 0.f));
        }
    }

    // same-wave DS ordering: reads below see this wave's writes above (no barrier needed)
    short8 af[2][4];
#pragma unroll
    for (int mt = 0; mt < 2; ++mt)
#pragma unroll
        for (int kk = 0; kk < 4; ++kk)
            af[mt][kk] = *(const short8*)&sl[SIDX(mt*16 + llo, kk*32 + lhi*8)];

    int spv[2][4];
#pragma unroll
    for (int mt = 0; mt < 2; ++mt)
#pragma unroll
        for (int e = 0; e < 4; ++e)
            spv[mt][e] = sport[r0w + mt*16 + lhi*4 + e];

    // ============ experts: per-s GEMM + immediate cndmask-select into h ============
    float h[2][4][4];   // [mt][nt][e], selected expert output + bias
#pragma unroll
    for (int s = 0; s < 3; ++s) {
        f32x4 ac[2][4];
#pragma unroll
        for (int mt = 0; mt < 2; ++mt)
#pragma unroll
            for (int nt = 0; nt < 4; ++nt) ac[mt][nt] = (f32x4){0.f,0.f,0.f,0.f};
#pragma unroll
        for (int nt = 0; nt < 4; ++nt) {
#pragma unroll
            for (int kk = 0; kk < 4; ++kk) {
                const short8 b = *(const short8*)(wexF + ((s*4 + kk)*4 + nt)*512 + lane*8);
                ac[0][nt] = __builtin_amdgcn_mfma_f32_16x16x32_bf16(af[0][kk], b, ac[0][nt], 0, 0, 0);
                ac[1][nt] = __builtin_amdgcn_mfma_f32_16x16x32_bf16(af[1][kk], b, ac[1][nt], 0, 0, 0);
            }
        }
#pragma unroll
        for (int nt = 0; nt < 4; ++nt) {
            const float bb = bexp[s*64 + nt*16 + llo];
#pragma unroll
            for (int mt = 0; mt < 2; ++mt)
#pragma unroll
                for (int e = 0; e < 4; ++e) {
                    const float cand = ac[mt][nt][e] + bb;
                    const bool take = (spv[mt][e] == s);
                    h[mt][nt][e] = (s == 0) ? (take ? cand : 0.f)
                                            : (take ? cand : h[mt][nt][e]);
                }
        }
    }

    // ============ tail: LayerNorm + ReLU + head + sigmoid (16-lane shuffles) ============
    float wo[4], lg0[4], lg1[4], lg2[4], lb0[4], lb1[4], lb2[4];
#pragma unroll
    for (int nt = 0; nt < 4; ++nt) {
        const int col = nt*16 + llo;
        wo[nt]  = wout[col];
        lg0[nt] = ln_g[col];       lb0[nt] = ln_b[col];
        lg1[nt] = ln_g[64 + col];  lb1[nt] = ln_b[64 + col];
        lg2[nt] = ln_g[128 + col]; lb2[nt] = ln_b[128 + col];
    }
    const float bo0 = bo[0];

#pragma unroll
    for (int mt = 0; mt < 2; ++mt) {
#pragma unroll
        for (int e = 0; e < 4; ++e) {
            const int sp = spv[mt][e];
            float m = (h[mt][0][e] + h[mt][1][e]) + (h[mt][2][e] + h[mt][3][e]);
            m += __shfl_xor(m, 1); m += __shfl_xor(m, 2); m += __shfl_xor(m, 4); m += __shfl_xor(m, 8);
            m *= (1.0f / 64.0f);
            float vv = 0.f;
#pragma unroll
            for (int nt = 0; nt < 4; ++nt) { const float c = h[mt][nt][e] - m; vv = fmaf(c, c, vv); }
            vv += __shfl_xor(vv, 1); vv += __shfl_xor(vv, 2); vv += __shfl_xor(vv, 4); vv += __shfl_xor(vv, 8);
            const float inv = rsqrtf(vv * (1.0f / 64.0f) + EPSV);
            float z = 0.f;
#pragma unroll
            for (int nt = 0; nt < 4; ++nt) {
                const float g_ = (sp == 0) ? lg0[nt] : (sp == 1 ? lg1[nt] : lg2[nt]);
                const float b_ = (sp == 0) ? lb0[nt] : (sp == 1 ? lb1[nt] : lb2[nt]);
                float hn = fmaf((h[mt][nt][e] - m) * inv, g_, b_);
                hn = fmaxf(hn, 0.f);
                z  = fmaf(hn, wo[nt], z);
            }
            z += __shfl_xor(z, 1); z += __shfl_xor(z, 2); z += __shfl_xor(z, 4); z += __shfl_xor(z, 8);
            if (llo == 0) out[r0w + mt*16 + lhi*4 + e] = 1.0f / (1.0f + __expf(-(z + bo0)));
        }
    }
}

extern "C" void kernel_launch(void* const* d_in, const int* in_sizes, int n_in,
                              void* d_out, int out_size, void* d_ws, size_t ws_size,
                              hipStream_t stream) {
    const int*   home  = (const int*)  d_in[0];
    const int*   away  = (const int*)  d_in[1];
    const float* gf    = (const float*)d_in[2];
    const int*   sport = (const int*)  d_in[3];
    const float* emb_h = (const float*)d_in[4];
    const float* emb_a = (const float*)d_in[5];
    const float* W_gf  = (const float*)d_in[6];
    const float* b_gf  = (const float*)d_in[7];
    const float* W_sh  = (const float*)d_in[8];
    const float* b_sh  = (const float*)d_in[9];
    const float* bn_g  = (const float*)d_in[10];
    const float* bn_b  = (const float*)d_in[11];
    const float* bn_m  = (const float*)d_in[12];
    const float* bn_v  = (const float*)d_in[13];
    const float* Wexp  = (const float*)d_in[14];
    const float* bexp  = (const float*)d_in[15];
    const float* ln_g  = (const float*)d_in[16];
    const float* ln_b  = (const float*)d_in[17];
    const float* wout  = (const float*)d_in[18];
    const float* bo    = (const float*)d_in[19];
    float* out = (float*)d_out;
    unsigned char* ws = (unsigned char*)d_ws;     // needs 67840 B

    const int B = in_sizes[0];                    // 262144 = 2048 * 128

    prep_kernel<<<128, 256, 0, stream>>>(W_gf, W_sh, b_sh, bn_g, bn_b, bn_m, bn_v, Wexp, ws);
    fused_kernel<<<B / 128, 256, 0, stream>>>(home, away, gf, sport, emb_h, emb_a,
                                              b_gf, bexp, ln_g, ln_b, wout, bo, ws, out);
}

// Round 10
// 146.138 us; speedup vs baseline: 1.2256x; 1.2256x over previous
//
#include <hip/hip_runtime.h>
#include <hip/hip_bf16.h>
#include <stdint.h>

#define DEV_INLINE __device__ __forceinline__

typedef short          short8 __attribute__((ext_vector_type(8)));   // MFMA A/B operand (8 bf16)
typedef unsigned short u16;
typedef unsigned short u16x8  __attribute__((ext_vector_type(8)));
typedef float          f32x4  __attribute__((ext_vector_type(4)));

constexpr float EPSV = 1e-5f;

// ---- d_ws layout (bytes) ----
//     0 : Wsh  frags bf16[16][64][8]  fid = kk*8+nt            (16384 B)
// 16384 : Wexp frags bf16[48][64][8]  fid = (s*4+kk)*4+nt      (49152 B)
// 65536 : sc[128] f32   (bn_gamma * rsqrt(var+eps))            (512 B)
// 66048 : sh[128] f32   ((b_sh-mean)*sc + bn_beta)             (512 B)
// 66560 : W_gfp[20][16] f32, row 19 = 0                        (1280 B)

static DEV_INLINE u16 f2bf(float f) {
    return __builtin_bit_cast(u16, __float2bfloat16(f));   // RNE
}

// B-fragment convention (HW-verified r4): frag (kk,nt), lane l, elem j:
//   value = W[k = kk*32 + (l>>4)*8 + j][col = nt*16 + (l&15)].
__global__ void prep_kernel(const float* __restrict__ W_gf,
                            const float* __restrict__ W_sh, const float* __restrict__ b_sh,
                            const float* __restrict__ bn_g, const float* __restrict__ bn_b,
                            const float* __restrict__ bn_m, const float* __restrict__ bn_v,
                            const float* __restrict__ Wexp,
                            unsigned char* __restrict__ ws)
{
    const int gid = blockIdx.x * blockDim.x + threadIdx.x;   // 32768 threads
    u16*   wshF = (u16*)ws;
    u16*   wexF = (u16*)(ws + 16384);
    float* scp  = (float*)(ws + 65536);
    float* shp  = (float*)(ws + 66048);
    float* wgp  = (float*)(ws + 66560);

    if (gid < 8192) {                       // Wsh frags (K padded 48->64 with zeros)
        const int fid = gid >> 9, l = (gid >> 3) & 63, j = gid & 7;
        const int kk = fid >> 3, nt = fid & 7;
        const int k = kk*32 + ((l >> 4) << 3) + j;
        const int c = nt*16 + (l & 15);
        wshF[gid] = f2bf((k < 48) ? W_sh[k*128 + c] : 0.f);
    } else {                                // Wexp frags, all K=128 real
        const int id = gid - 8192;
        const int fid = id >> 9, l = (id >> 3) & 63, j = id & 7;
        const int s = fid >> 4, kk = (fid >> 2) & 3, nt = fid & 3;
        const int k = kk*32 + ((l >> 4) << 3) + j;
        const int d = nt*16 + (l & 15);
        wexF[id] = f2bf(Wexp[s*8192 + k*64 + d]);
    }
    if (gid < 128) {
        const float sc = bn_g[gid] * rsqrtf(bn_v[gid] + EPSV);
        scp[gid] = sc;
        shp[gid] = (b_sh[gid] - bn_m[gid]) * sc + bn_b[gid];
    }
    if (gid < 320) {                        // padded W_gf (20 rows, row 19 zero)
        const int f = gid >> 4, e = gid & 15;
        wgp[gid] = (f < 19) ? W_gf[f*16 + e] : 0.f;
    }
}

// swizzled per-wave S slice [32 r][128 j] bf16; 16B-group XOR -> conflict-free b128
#define SIDX(r,j)  (((r)<<7) + ((((j)>>3) ^ ((r)&15))<<3) + ((j)&7))
// tail h slice [32 r][64 c] f32: 16 slots of 16B per row, XOR-swizzled
static DEV_INLINE int hswz(int rho) { return (rho & 15) ^ ((rho & 8) >> 1); }

__global__ __launch_bounds__(256) void fused_kernel(
    const int*   __restrict__ home,  const int* __restrict__ away,
    const float* __restrict__ gfeat, const int* __restrict__ sport,
    const float* __restrict__ emb_h, const float* __restrict__ emb_a,
    const float* __restrict__ b_gf,
    const float* __restrict__ bexp,
    const float* __restrict__ ln_g,  const float* __restrict__ ln_b,
    const float* __restrict__ wout,  const float* __restrict__ bo,
    const unsigned char* __restrict__ ws,
    float* __restrict__ out)
{
    __shared__ int cntS[3], curS[3], baseS[2];
    __shared__ unsigned short prm[128];
    __shared__ float lnGl[192], lnBl[192], wol[64];
    __shared__ __align__(16) unsigned char shb[4][8192];   // per-wave: S (bf16) then h (f32)

    const int tid  = threadIdx.x;
    const int lane = tid & 63;
    const int w    = tid >> 6;
    const int llo  = lane & 15;
    const int lhi  = lane >> 4;
    const int r0   = blockIdx.x * 128;

    const u16*   wshF = (const u16*)ws;
    const u16*   wexF = (const u16*)(ws + 16384);
    const float* scp  = (const float*)(ws + 65536);
    const float* shp  = (const float*)(ws + 66048);
    const float* wgp  = (const float*)(ws + 66560);

    // ============ in-block 3-bucket sport compaction (+ param staging on other half) ======
    if (tid < 3) { cntS[tid] = 0; curS[tid] = 0; }
    __syncthreads();
    int mysp = 0;
    if (tid < 128) {
        mysp = sport[r0 + tid];
        atomicAdd(&cntS[mysp], 1);
    } else {
        for (int i = tid - 128; i < 448; i += 128) {
            if (i < 192)      lnGl[i]       = ln_g[i];
            else if (i < 384) lnBl[i - 192] = ln_b[i - 192];
            else              wol[i - 384]  = wout[i - 384];
        }
    }
    __syncthreads();
    if (tid == 0) { baseS[0] = cntS[0]; baseS[1] = cntS[0] + cntS[1]; }
    __syncthreads();
    if (tid < 128) {
        const int base = (mysp == 0) ? 0 : ((mysp == 1) ? baseS[0] : baseS[1]);
        prm[base + atomicAdd(&curS[mysp], 1)] = (unsigned short)tid;
    }
    __syncthreads();

    const int b1 = baseS[0], b2 = baseS[1];
    const int posW = w * 32;
    // wave-uniform sport range (rows sorted by sport within block)
    const int spF = __builtin_amdgcn_readfirstlane((posW      >= b1) + (posW      >= b2));
    const int spL = __builtin_amdgcn_readfirstlane((posW + 31 >= b1) + (posW + 31 >= b2));

    const int pr0 = prm[posW + llo];            // local row of A-tile mt=0, lane row llo
    const int pr1 = prm[posW + 16 + llo];       // mt=1
    const int rA0 = r0 + pr0, rA1 = r0 + pr1;

    // ============ build A-fragments directly in registers ============
    short8 a[2][2];
    {   // kk=0: [home emb | away emb]; lane's 8-elem slice = one 32B half-row
        const int*   idxp = (lhi < 2) ? home  : away;
        const float* tab  = (lhi < 2) ? emb_h : emb_a;
        const int    off  = (lhi & 1) * 8;
#pragma unroll
        for (int mt = 0; mt < 2; ++mt) {
            const int r = mt ? rA1 : rA0;
            const float* rp = tab + (size_t)idxp[r] * 16 + off;
            const float4 v0 = *(const float4*)rp;
            const float4 v1 = *(const float4*)(rp + 4);
            u16x8 p;
            p[0]=f2bf(v0.x); p[1]=f2bf(v0.y); p[2]=f2bf(v0.z); p[3]=f2bf(v0.w);
            p[4]=f2bf(v1.x); p[5]=f2bf(v1.y); p[6]=f2bf(v1.z); p[7]=f2bf(v1.w);
            a[mt][0] = __builtin_bit_cast(short8, p);
        }
    }
    {   // kk=1: relu(gf @ W_gf + b) cols 32..47, zero pad 48..63; f-split across lane^32
        const int eo = (lhi & 1) * 8;
        const int f0 = (lhi >> 1) * 10;
        float p0[8] = {0,0,0,0,0,0,0,0}, p1[8] = {0,0,0,0,0,0,0,0};
#pragma unroll
        for (int i = 0; i < 10; ++i) {
            const int f  = f0 + i;
            const int fc = (f < 19) ? f : 18;          // safe addr; wgp row 19 is zero
            const float4 w0 = *(const float4*)(wgp + f*16 + eo);
            const float4 w1 = *(const float4*)(wgp + f*16 + eo + 4);
            const float g0 = gfeat[(size_t)rA0 * 19 + fc];
            const float g1 = gfeat[(size_t)rA1 * 19 + fc];
            p0[0]=fmaf(g0,w0.x,p0[0]); p0[1]=fmaf(g0,w0.y,p0[1]); p0[2]=fmaf(g0,w0.z,p0[2]); p0[3]=fmaf(g0,w0.w,p0[3]);
            p0[4]=fmaf(g0,w1.x,p0[4]); p0[5]=fmaf(g0,w1.y,p0[5]); p0[6]=fmaf(g0,w1.z,p0[6]); p0[7]=fmaf(g0,w1.w,p0[7]);
            p1[0]=fmaf(g1,w0.x,p1[0]); p1[1]=fmaf(g1,w0.y,p1[1]); p1[2]=fmaf(g1,w0.z,p1[2]); p1[3]=fmaf(g1,w0.w,p1[3]);
            p1[4]=fmaf(g1,w1.x,p1[4]); p1[5]=fmaf(g1,w1.y,p1[5]); p1[6]=fmaf(g1,w1.z,p1[6]); p1[7]=fmaf(g1,w1.w,p1[7]);
        }
        const float4 bg0 = *(const float4*)(b_gf + eo);
        const float4 bg1 = *(const float4*)(b_gf + eo + 4);
        const float bg[8] = {bg0.x,bg0.y,bg0.z,bg0.w,bg1.x,bg1.y,bg1.z,bg1.w};
        u16x8 q0, q1;
#pragma unroll
        for (int j = 0; j < 8; ++j) {
            const float s0 = p0[j] + __shfl_xor(p0[j], 32);
            const float s1 = p1[j] + __shfl_xor(p1[j], 32);
            q0[j] = (lhi < 2) ? f2bf(fmaxf(s0 + bg[j], 0.f)) : (u16)0;
            q1[j] = (lhi < 2) ? f2bf(fmaxf(s1 + bg[j], 0.f)) : (u16)0;
        }
        a[0][1] = __builtin_bit_cast(short8, q0);
        a[1][1] = __builtin_bit_cast(short8, q1);
    }

    // ============ S = X @ Wsh, BN+ReLU fold -> wave-private LDS slice (bf16) ============
    u16* sl = (u16*)shb[w];
#pragma unroll
    for (int nt = 0; nt < 8; ++nt) {
        const short8 b0  = *(const short8*)(wshF + (0*8 + nt)*512 + lane*8);
        const short8 b1f = *(const short8*)(wshF + (1*8 + nt)*512 + lane*8);
        f32x4 c0 = {0.f,0.f,0.f,0.f}, c1 = {0.f,0.f,0.f,0.f};
        c0 = __builtin_amdgcn_mfma_f32_16x16x32_bf16(a[0][0], b0,  c0, 0, 0, 0);
        c0 = __builtin_amdgcn_mfma_f32_16x16x32_bf16(a[0][1], b1f, c0, 0, 0, 0);
        c1 = __builtin_amdgcn_mfma_f32_16x16x32_bf16(a[1][0], b0,  c1, 0, 0, 0);
        c1 = __builtin_amdgcn_mfma_f32_16x16x32_bf16(a[1][1], b1f, c1, 0, 0, 0);
        const int col = nt*16 + llo;
        const float sc = scp[col], sh = shp[col];
#pragma unroll
        for (int e = 0; e < 4; ++e) {
            sl[SIDX(lhi*4 + e,      col)] = f2bf(fmaxf(fmaf(c0[e], sc, sh), 0.f));
            sl[SIDX(16 + lhi*4 + e, col)] = f2bf(fmaxf(fmaf(c1[e], sc, sh), 0.f));
        }
    }

    // same-wave DS ordering: no barrier needed
    short8 af[2][4];
#pragma unroll
    for (int mt = 0; mt < 2; ++mt)
#pragma unroll
        for (int kk = 0; kk < 4; ++kk)
            af[mt][kk] = *(const short8*)&sl[SIDX(mt*16 + llo, kk*32 + lhi*8)];

    // per-(mt,e) row sport from compacted position (no gather)
    int spr[2][4];
#pragma unroll
    for (int mt = 0; mt < 2; ++mt)
#pragma unroll
        for (int e = 0; e < 4; ++e) {
            const int pos = posW + mt*16 + lhi*4 + e;
            spr[mt][e] = (pos >= b1) + (pos >= b2);
        }

    // ============ experts (skip sports absent from this wave) + select into h ============
    float h[2][4][4] = {};   // [mt][nt][e]
#pragma unroll
    for (int s = 0; s < 3; ++s) {
        if (s < spF || s > spL) continue;    // wave-uniform skip (s_cbranch)
        f32x4 ac[2][4];
#pragma unroll
        for (int mt = 0; mt < 2; ++mt)
#pragma unroll
            for (int nt = 0; nt < 4; ++nt) ac[mt][nt] = (f32x4){0.f,0.f,0.f,0.f};
#pragma unroll
        for (int nt = 0; nt < 4; ++nt) {
#pragma unroll
            for (int kk = 0; kk < 4; ++kk) {
                const short8 b = *(const short8*)(wexF + ((s*4 + kk)*4 + nt)*512 + lane*8);
                ac[0][nt] = __builtin_amdgcn_mfma_f32_16x16x32_bf16(af[0][kk], b, ac[0][nt], 0, 0, 0);
                ac[1][nt] = __builtin_amdgcn_mfma_f32_16x16x32_bf16(af[1][kk], b, ac[1][nt], 0, 0, 0);
            }
        }
#pragma unroll
        for (int nt = 0; nt < 4; ++nt) {
            const float bb = bexp[s*64 + nt*16 + llo];
#pragma unroll
            for (int mt = 0; mt < 2; ++mt)
#pragma unroll
                for (int e = 0; e < 4; ++e) {
                    const float cand = ac[mt][nt][e] + bb;
                    h[mt][nt][e] = (spr[mt][e] == s) ? cand : h[mt][nt][e];
                }
        }
    }

    // ============ tail: h -> LDS (f32, swizzled), row-parallel LN + head ============
    float* hb = (float*)shb[w];              // S slice dead (af consumed); reuse as f32 h
#pragma unroll
    for (int mt = 0; mt < 2; ++mt)
#pragma unroll
        for (int nt = 0; nt < 4; ++nt)
#pragma unroll
            for (int e = 0; e < 4; ++e) {
                const int rho  = mt*16 + lhi*4 + e;
                const int sraw = nt*4 + (llo >> 2);
                const int slot = sraw ^ hswz(rho);
                hb[rho*64 + slot*4 + (llo & 3)] = h[mt][nt][e];
            }

    {
        const int rho = lane & 31, hf = lane >> 5;   // lane -> (row, half)
        float v[32];
#pragma unroll
        for (int j2 = 0; j2 < 8; ++j2) {
            const int j = hf*8 + j2;
            const int slot = j ^ hswz(rho);
            const float4 q = *(const float4*)&hb[rho*64 + slot*4];
            v[j2*4+0]=q.x; v[j2*4+1]=q.y; v[j2*4+2]=q.z; v[j2*4+3]=q.w;
        }
        float sm = 0.f;
#pragma unroll
        for (int i = 0; i < 32; ++i) sm += v[i];
        sm += __shfl_xor(sm, 32);
        const float m = sm * (1.0f / 64.0f);
        float vv = 0.f;
#pragma unroll
        for (int i = 0; i < 32; ++i) { const float c = v[i] - m; vv = fmaf(c, c, vv); }
        vv += __shfl_xor(vv, 32);
        const float inv = rsqrtf(vv * (1.0f / 64.0f) + EPSV);

        const int pos = posW + rho;
        const int sp  = (pos >= b1) + (pos >= b2);
        const float* lg = lnGl + sp*64 + hf*32;
        const float* lb = lnBl + sp*64 + hf*32;
        const float* wo = wol  + hf*32;
        float z = 0.f;
#pragma unroll
        for (int q2 = 0; q2 < 8; ++q2) {
            const float4 g4 = *(const float4*)(lg + q2*4);
            const float4 b4 = *(const float4*)(lb + q2*4);
            const float4 w4 = *(const float4*)(wo + q2*4);
            float hn;
            hn = fmaxf(fmaf((v[q2*4+0]-m)*inv, g4.x, b4.x), 0.f); z = fmaf(hn, w4.x, z);
            hn = fmaxf(fmaf((v[q2*4+1]-m)*inv, g4.y, b4.y), 0.f); z = fmaf(hn, w4.y, z);
            hn = fmaxf(fmaf((v[q2*4+2]-m)*inv, g4.z, b4.z), 0.f); z = fmaf(hn, w4.z, z);
            hn = fmaxf(fmaf((v[q2*4+3]-m)*inv, g4.w, b4.w), 0.f); z = fmaf(hn, w4.w, z);
        }
        z += __shfl_xor(z, 32);
        if (hf == 0) {
            const int rl = prm[posW + rho];
            out[r0 + rl] = 1.0f / (1.0f + __expf(-(z + bo[0])));
        }
    }
}

extern "C" void kernel_launch(void* const* d_in, const int* in_sizes, int n_in,
                              void* d_out, int out_size, void* d_ws, size_t ws_size,
                              hipStream_t stream) {
    const int*   home  = (const int*)  d_in[0];
    const int*   away  = (const int*)  d_in[1];
    const float* gf    = (const float*)d_in[2];
    const int*   sport = (const int*)  d_in[3];
    const float* emb_h = (const float*)d_in[4];
    const float* emb_a = (const float*)d_in[5];
    const float* W_gf  = (const float*)d_in[6];
    const float* b_gf  = (const float*)d_in[7];
    const float* W_sh  = (const float*)d_in[8];
    const float* b_sh  = (const float*)d_in[9];
    const float* bn_g  = (const float*)d_in[10];
    const float* bn_b  = (const float*)d_in[11];
    const float* bn_m  = (const float*)d_in[12];
    const float* bn_v  = (const float*)d_in[13];
    const float* Wexp  = (const float*)d_in[14];
    const float* bexp  = (const float*)d_in[15];
    const float* ln_g  = (const float*)d_in[16];
    const float* ln_b  = (const float*)d_in[17];
    const float* wout  = (const float*)d_in[18];
    const float* bo    = (const float*)d_in[19];
    float* out = (float*)d_out;
    unsigned char* ws = (unsigned char*)d_ws;     // needs 67840 B

    const int B = in_sizes[0];                    // 262144 = 2048 * 128

    prep_kernel<<<128, 256, 0, stream>>>(W_gf, W_sh, b_sh, bn_g, bn_b, bn_m, bn_v, Wexp, ws);
    fused_kernel<<<B / 128, 256, 0, stream>>>(home, away, gf, sport, emb_h, emb_a,
                                              b_gf, bexp, ln_g, ln_b, wout, bo, ws, out);
}